// Round 12
// baseline (128.011 us; speedup 1.0000x reference)
//
#include <hip/hip_runtime.h>
#include <math.h>

#define B_    8
#define T_    2000
#define H_    256
#define FOUT_ 257
#define ALEN_ 128

typedef __attribute__((ext_vector_type(8))) short bf16x8;
typedef __attribute__((ext_vector_type(4))) float f32x4;
typedef __attribute__((ext_vector_type(16))) float f32x16;
typedef __attribute__((ext_vector_type(8))) unsigned short u16x8;

// ---------------------------------------------------------------------------
// truncation split: x = hi + lo exactly at f32
__device__ __forceinline__ void split1(float x, unsigned short& h, unsigned short& l) {
    unsigned u = __builtin_bit_cast(unsigned, x);
    h = (unsigned short)(u >> 16);
    float hf = __builtin_bit_cast(float, u & 0xFFFF0000u);
    l = (unsigned short)(__builtin_bit_cast(unsigned, x - hf) >> 16);
}
__device__ __forceinline__ void split8(float4 f0, float4 f1, bf16x8& h, bf16x8& l) {
    float f[8] = {f0.x, f0.y, f0.z, f0.w, f1.x, f1.y, f1.z, f1.w};
#pragma unroll
    for (int i = 0; i < 8; ++i) {
        unsigned short hh, ll;
        split1(f[i], hh, ll);
        h[i] = (short)hh; l[i] = (short)ll;
    }
}
__device__ __forceinline__ void gld16(const void* g, void* l) {
    __builtin_amdgcn_global_load_lds(
        (const __attribute__((address_space(1))) unsigned*)g,
        (__attribute__((address_space(3))) unsigned*)l, 16, 0, 0);
}

// ---------------------------------------------------------------------------
// prep:
//  [0,2000):    qsplit  q -> q2h/q2l
//  [2000,3008): k -> kh/kl (row-major split) + ktn (PV-frag-ordered bf16-hi)
//  [3008,3264): W_score -> wsn frag-ordered (attn phase0 B)
//  [3264,3776): W_enh -> wen frag-ordered for gemm main loop B:
//               wen[kt(8)][nq(8)][kc(4)][lh(2)][lm(32)][e(8)],
//               elem = We[nq*32+lm][kt*64+kc*16+lh*8+e]
//  [3776,4288): W_mask -> wmn frag-ordered (stage-2 B); rows 257..319 zero.
__global__ __launch_bounds__(256) void prep(
    const float* __restrict__ k, const float* __restrict__ q,
    const float* __restrict__ Ws, const float* __restrict__ We,
    const float* __restrict__ Wm,
    unsigned short* __restrict__ q2h, unsigned short* __restrict__ q2l,
    unsigned short* __restrict__ kh, unsigned short* __restrict__ kl,
    unsigned short* __restrict__ ktn,
    unsigned short* __restrict__ wsnh, unsigned short* __restrict__ wsnl,
    unsigned short* __restrict__ wenh, unsigned short* __restrict__ wenl,
    unsigned short* __restrict__ wmnh, unsigned short* __restrict__ wmnl)
{
    __shared__ float tile[16][260];
    const int bx = blockIdx.x, tid = threadIdx.x;

    if (bx < 2000) {                     // ---- qsplit
        const size_t i = ((size_t)bx * 256 + tid) * 8;
        const float4 f0 = *(const float4*)(q + i);
        const float4 f1 = *(const float4*)(q + i + 4);
        bf16x8 h, l;
        split8(f0, f1, h, l);
        *(bf16x8*)(q2h + i) = h;
        *(bf16x8*)(q2l + i) = l;
    } else if (bx < 3008) {              // ---- k prep
        const int bid = bx - 2000;
        const int b = bid / 126;
        const int g = bid % 126;
        const int s0 = g * 16;
        const int r = tid >> 4, cs = (tid & 15) * 16;
        const int s = s0 + r;
        if (s < T_) {
            const size_t ko = ((size_t)b * T_ + s) * H_ + cs;
            const float* src = k + ko;
#pragma unroll
            for (int i = 0; i < 2; ++i) {
                const float4 v0 = *(const float4*)(src + i * 8);
                const float4 v1 = *(const float4*)(src + i * 8 + 4);
                bf16x8 h, l;
                split8(v0, v1, h, l);
                *(bf16x8*)(kh + ko + i * 8) = h;
                *(bf16x8*)(kl + ko + i * 8) = l;
                const float ff[8] = {v0.x, v0.y, v0.z, v0.w, v1.x, v1.y, v1.z, v1.w};
#pragma unroll
                for (int j = 0; j < 8; ++j) tile[r][cs + i * 8 + j] = ff[j];
            }
        } else {
#pragma unroll
            for (int i = 0; i < 16; ++i) tile[r][cs + i] = 0.f;
        }
        __syncthreads();
        const int h = tid;
        const int ht = h >> 4, lq = h & 15;
        u16x8 o0, o1;
#pragma unroll
        for (int ss = 0; ss < 8; ++ss)
            o0[ss] = (unsigned short)(__builtin_bit_cast(unsigned, tile[ss][h]) >> 16);
#pragma unroll
        for (int ss = 0; ss < 8; ++ss)
            o1[ss] = (unsigned short)(__builtin_bit_cast(unsigned, tile[ss + 8][h]) >> 16);
        unsigned short* dst = ktn + (((size_t)(b * 16 + ht) * 126) + g) * 256 + lq * 8;
        *(u16x8*)(dst) = o0;
        *(u16x8*)(dst + 128) = o1;
    } else if (bx < 3264) {              // ---- W_score -> wsn
        const int g = bx - 3008;
        const int hcol = tid;
        unsigned short h, l; split1(Ws[g * 256 + hcol], h, l);
        const int ht = g >> 4, lq = g & 15;
        const int kg = hcol >> 5, lk = (hcol >> 3) & 3, e = hcol & 7;
        const int off = ((ht * 8 + kg) * 64 + lk * 16 + lq) * 8 + e;
        wsnh[off] = h; wsnl[off] = l;
    } else if (bx < 3776) {              // ---- W_enh -> wen frag-ordered
        const int idx = (bx - 3264) * 256 + tid;  // 0..131071
        const int n = idx >> 9;           // 0..255 (enh col)
        const int kk = idx & 511;         // 0..511
        unsigned short h, l; split1(We[idx], h, l);
        const int kt = kk >> 6, kc = (kk >> 4) & 3, lh2 = (kk >> 3) & 1, e = kk & 7;
        const int nq = n >> 5, lm2 = n & 31;
        const int off = ((((kt * 8 + nq) * 4 + kc) * 2 + lh2) * 32 + lm2) * 8 + e;
        wenh[off] = h; wenl[off] = l;
    } else {                             // ---- W_mask -> wmn (rows < 320)
        const int r2 = bx - 3776;        // row (out col) 0..511
        if (r2 < 320) {
            const float x = (r2 < FOUT_) ? Wm[r2 * 256 + tid] : 0.f;
            unsigned short h, l; split1(x, h, l);
            const int nt = r2 >> 5, lm2 = r2 & 31;
            const int f = tid >> 4, hh2 = (tid >> 3) & 1, e = tid & 7;
            const int off = (((nt * 16 + f) * 2 + hh2) * 32 + lm2) * 8 + e;
            wmnh[off] = h; wmnl[off] = l;
        }
    }
}

// ---------------------------------------------------------------------------
// Fused banded attention (R11-proven, unchanged): phase0 qs-GEMM in-block,
// QK^T from kh/kl, band softmax, PV from frag-ordered ktn. XCD-local b=bid&7.
__global__ __launch_bounds__(256) void band_attn_mfma(
    const unsigned short* __restrict__ q2h, const unsigned short* __restrict__ q2l,
    const unsigned short* __restrict__ wsnh, const unsigned short* __restrict__ wsnl,
    const unsigned short* __restrict__ kh, const unsigned short* __restrict__ kl,
    const unsigned short* __restrict__ ktn,
    unsigned short* __restrict__ Ch, unsigned short* __restrict__ Cl)
{
    __shared__ float S[16][164];
    __shared__ unsigned short PH[16][168];
    __shared__ unsigned short PL[16][168];
    __shared__ unsigned short QSH[16 * 256];
    __shared__ unsigned short QSL[16 * 256];

    const int bid = blockIdx.x;
    const int b = bid & 7;
    const int t0 = (bid >> 3) * 16;
    const int tid = threadIdx.x;
    const int w = tid >> 6, l = tid & 63;
    const int lq = l & 15;
    const int lk = l >> 4;
    const int s_lo = max(0, t0 - ALEN_);
    const size_t qrow = (size_t)b * T_ + t0;
    const size_t kb = (size_t)b * T_ * H_;

    // ---- phase 0: qs tile = q2[16 rows] @ Ws^T (3-term), D -> LDS ----
    {
        bf16x8 aH[8], aL[8];
#pragma unroll
        for (int kg = 0; kg < 8; ++kg) {
            const size_t o = (qrow + lq) * H_ + kg * 32 + lk * 8;
            aH[kg] = *(const bf16x8*)(q2h + o);
            aL[kg] = *(const bf16x8*)(q2l + o);
        }
        for (int ht = w; ht < 16; ht += 4) {
            f32x4 acc = {};
#pragma unroll
            for (int kg = 0; kg < 8; ++kg) {
                const int fo = ((ht * 8 + kg) * 64 + lk * 16 + lq) * 8;
                const bf16x8 bh = *(const bf16x8*)(wsnh + fo);
                const bf16x8 bl = *(const bf16x8*)(wsnl + fo);
                acc = __builtin_amdgcn_mfma_f32_16x16x32_bf16(aH[kg], bh, acc, 0, 0, 0);
                acc = __builtin_amdgcn_mfma_f32_16x16x32_bf16(aH[kg], bl, acc, 0, 0, 0);
                acc = __builtin_amdgcn_mfma_f32_16x16x32_bf16(aL[kg], bh, acc, 0, 0, 0);
            }
#pragma unroll
            for (int r = 0; r < 4; ++r) {
                unsigned short h2, l2;
                split1(acc[r], h2, l2);
                const int t = lk * 4 + r;
                unsigned off = (unsigned)(t * 512 + (ht * 16 + lq) * 2);
                off ^= (unsigned)((t & 7) << 4);
                *(unsigned short*)((char*)QSH + off) = h2;
                *(unsigned short*)((char*)QSL + off) = l2;
            }
        }
    }
    __syncthreads();

    // ---- QK^T ----
    bf16x8 aH[8], aL[8];
#pragma unroll
    for (int hc = 0; hc < 8; ++hc) {
        unsigned off = (unsigned)(lq * 512 + hc * 64 + lk * 16);
        off ^= (unsigned)((lq & 7) << 4);
        aH[hc] = *(const bf16x8*)((const char*)QSH + off);
        aL[hc] = *(const bf16x8*)((const char*)QSL + off);
    }
    for (int st = w; st < 9; st += 4) {
        f32x4 acc = {};
        const int s = s_lo + st * 16 + lq;
        const size_t ro = kb + (size_t)s * H_ + lk * 8;
#pragma unroll
        for (int hc = 0; hc < 8; ++hc) {
            const bf16x8 bh = *(const bf16x8*)(kh + ro + hc * 32);
            const bf16x8 bl = *(const bf16x8*)(kl + ro + hc * 32);
            acc = __builtin_amdgcn_mfma_f32_16x16x32_bf16(aH[hc], bh, acc, 0, 0, 0);
            acc = __builtin_amdgcn_mfma_f32_16x16x32_bf16(aH[hc], bl, acc, 0, 0, 0);
            acc = __builtin_amdgcn_mfma_f32_16x16x32_bf16(aL[hc], bh, acc, 0, 0, 0);
        }
#pragma unroll
        for (int r = 0; r < 4; ++r)
            S[lk * 4 + r][st * 16 + lq] = acc[r];
    }
    __syncthreads();

    // ---- softmax (band-masked, P pre-scaled by 1/denom) ----
    {
        const int q = tid >> 4, li = tid & 15;
        const int t = t0 + q;
        const int jlo = max(0, t - ALEN_) - s_lo;
        const int jhi = t - s_lo;
        float m = -INFINITY;
#pragma unroll
        for (int j = 0; j < 10; ++j) {
            const int s = li + j * 16;
            if (s >= jlo && s <= jhi) m = fmaxf(m, S[q][s]);
        }
#pragma unroll
        for (int off = 8; off; off >>= 1) m = fmaxf(m, __shfl_xor(m, off));
        float sum = 0.f;
#pragma unroll
        for (int j = 0; j < 10; ++j) {
            const int s = li + j * 16;
            const float e = (s >= jlo && s <= jhi) ? expf(S[q][s] - m) : 0.f;
            S[q][s] = e;
            sum += e;
        }
#pragma unroll
        for (int off = 8; off; off >>= 1) sum += __shfl_xor(sum, off);
        const float inv = 1.f / (sum + 1e-30f);
#pragma unroll
        for (int j = 0; j < 10; ++j) {
            const int s = li + j * 16;
            unsigned short hh2, ll2;
            split1(S[q][s] * inv, hh2, ll2);
            PH[q][s] = hh2;
            PL[q][s] = ll2;
        }
    }
    __syncthreads();

    // ---- PV (frag-ordered ktn) ----
    const int gbase = s_lo >> 4;
    for (int ht = w; ht < 16; ht += 4) {
        f32x4 acc = {};
        const unsigned short* ktb = ktn + ((size_t)(b * 16 + ht) * 126) * 256;
#pragma unroll
        for (int sc = 0; sc < 5; ++sc) {
            const bf16x8 ph = *(const bf16x8*)((const char*)&PH[lq][0] + sc * 64 + lk * 16);
            const bf16x8 pl = *(const bf16x8*)((const char*)&PL[lq][0] + sc * 64 + lk * 16);
            const bf16x8 bt = *(const bf16x8*)(
                ktb + (size_t)(gbase + 2 * sc + (lk >> 1)) * 256 + (lk & 1) * 128 + lq * 8);
            acc = __builtin_amdgcn_mfma_f32_16x16x32_bf16(ph, bt, acc, 0, 0, 0);
            acc = __builtin_amdgcn_mfma_f32_16x16x32_bf16(pl, bt, acc, 0, 0, 0);
        }
#pragma unroll
        for (int r = 0; r < 4; ++r) {
            unsigned short hh2, ll2;
            split1(acc[r], hh2, ll2);
            const size_t o = (qrow + lk * 4 + r) * H_ + ht * 16 + lq;
            Ch[o] = hh2;
            Cl[o] = ll2;
        }
    }
}

// ---------------------------------------------------------------------------
// Fused enh+out GEMM v2 (occupancy-first): BM=32, 500 blocks, 512 thr (8
// waves x one 32x32 wave tile). W never staged in LDS: B-frags read straight
// from frag-ordered wen (L2-resident, wave-contiguous 1KB). LDS = A dbuf
// (2x8KB, aliased by 32KB EH/EL after main loop). BK=64, NT=8 barriers.
// K-order and arithmetic identical to R11.
__global__ __launch_bounds__(512, 4) void gemm_enh_out(
    const unsigned short* __restrict__ Ah1, const unsigned short* __restrict__ Al1,
    const unsigned short* __restrict__ Ah2, const unsigned short* __restrict__ Al2,
    const unsigned short* __restrict__ wenh, const unsigned short* __restrict__ wenl,
    const float* __restrict__ b_enh,
    const unsigned short* __restrict__ wmnh, const unsigned short* __restrict__ wmnl,
    const float* __restrict__ b_mask, float* __restrict__ out)
{
    __shared__ char LDSB[32 * 1024];
    // main loop: AS buf0 @0 (8KB), buf1 @8K. after: EH @0 (16K), EL @16K.

    const int tid = threadIdx.x;
    const int m0 = blockIdx.x * 32;
    const int w = tid >> 6, l = tid & 63;
    const int lm = l & 31, lh = l >> 5;

    f32x16 acc = {};

    // A rows in LDS: 32 rows x 256B [hi 128 | lo 128], swizzle ^((row&7)<<4)
    // within each 128B half; applied on gld16 SOURCE (inverse) + frag reads.
    auto STAGEA = [&](int kt, int buf) {
        const int k0g = kt * 64;
        const unsigned short* Hs = Ah1;
        const unsigned short* Ls = Al1;
        int k0 = k0g;
        if (k0g >= 256) { Hs = Ah2; Ls = Al2; k0 = k0g - 256; }
        const unsigned D = (unsigned)tid * 16u;
        const unsigned row = D >> 8;            // 0..31
        const unsigned p = D & 255u;
        const unsigned half = p >> 7;
        const unsigned u = (p & 127u) ^ ((row & 7u) << 4);
        const unsigned kelem = u >> 1;          // 0..63, multiple of 8
        const unsigned short* src =
            (half ? Ls : Hs) + (size_t)(m0 + row) * 256 + k0 + kelem;
        gld16(src, LDSB + buf * 8192 + (size_t)w * 1024);
    };

    STAGEA(0, 0);
    __syncthreads();

    int buf = 0;
    for (int kt = 0; kt < 8; ++kt) {
        if (kt != 7) STAGEA(kt + 1, buf ^ 1);
        const char* As = LDSB + buf * 8192;
        const unsigned swa = (unsigned)((lm & 7) << 4);
#pragma unroll
        for (int kc = 0; kc < 4; ++kc) {
            const unsigned u = (unsigned)(kc * 32 + lh * 16);
            const bf16x8 ah = *(const bf16x8*)(As + lm * 256 + (u ^ swa));
            const bf16x8 al = *(const bf16x8*)(As + lm * 256 + 128 + (u ^ swa));
            const size_t bo = ((((size_t)(kt * 8 + w) * 4 + kc) * 2 + lh) * 32 + lm) * 8;
            const bf16x8 bh = *(const bf16x8*)(wenh + bo);
            const bf16x8 bl = *(const bf16x8*)(wenl + bo);
            acc = __builtin_amdgcn_mfma_f32_32x32x16_bf16(ah, bh, acc, 0, 0, 0);
            acc = __builtin_amdgcn_mfma_f32_32x32x16_bf16(ah, bl, acc, 0, 0, 0);
            acc = __builtin_amdgcn_mfma_f32_32x32x16_bf16(al, bh, acc, 0, 0, 0);
        }
        __syncthreads();
        buf ^= 1;
    }

    // enh tile -> LDS (split, swizzled). D: col=lane&31, row=(e&3)+8*(e>>2)+4*lh
    {
        char* EH = LDSB;
        char* EL = LDSB + 16384;
        const int col = w * 32 + lm;
        const float bv = b_enh[col];
#pragma unroll
        for (int e = 0; e < 16; ++e) {
            const int row = (e & 3) + 8 * (e >> 2) + 4 * lh;
            unsigned short h2, l2;
            split1(tanhf(acc[e] + bv), h2, l2);
            unsigned off = (unsigned)(row * 512 + col * 2);
            off ^= (unsigned)((row & 7) << 4);
            *(unsigned short*)(EH + off) = h2;
            *(unsigned short*)(EL + off) = l2;
        }
    }
    __syncthreads();

    // out = sigmoid(enh @ Wm^T + bm); wave w: nt = w (and w+8 for w<2)
    for (int nt = w; nt < 10; nt += 8) {
        const char* EH = LDSB;
        const char* EL = LDSB + 16384;
        f32x16 o = {};
        const unsigned sw = (unsigned)((lm & 7) << 4);
#pragma unroll
        for (int f = 0; f < 16; ++f) {
            const unsigned offA = (unsigned)(lm * 512 + f * 32 + lh * 16);
            const bf16x8 ah = *(const bf16x8*)(EH + (offA ^ sw));
            const bf16x8 al = *(const bf16x8*)(EL + (offA ^ sw));
            const size_t bo = (((size_t)(nt * 16 + f) * 2 + lh) * 32 + lm) * 8;
            const bf16x8 bh = *(const bf16x8*)(wmnh + bo);
            const bf16x8 bl = *(const bf16x8*)(wmnl + bo);
            o = __builtin_amdgcn_mfma_f32_32x32x16_bf16(ah, bh, o, 0, 0, 0);
            o = __builtin_amdgcn_mfma_f32_32x32x16_bf16(ah, bl, o, 0, 0, 0);
            o = __builtin_amdgcn_mfma_f32_32x32x16_bf16(al, bh, o, 0, 0, 0);
        }
        const int gcol = nt * 32 + lm;
        if (gcol < FOUT_) {
            const float bv = b_mask[gcol];
#pragma unroll
            for (int e = 0; e < 16; ++e) {
                const int rowl = (e & 3) + 8 * (e >> 2) + 4 * lh;
                out[(size_t)(m0 + rowl) * FOUT_ + gcol] = 1.f / (1.f + expf(-(o[e] + bv)));
            }
        }
    }
}

// ---------------------------------------------------------------------------
extern "C" void kernel_launch(void* const* d_in, const int* in_sizes, int n_in,
                              void* d_out, int out_size, void* d_ws, size_t ws_size,
                              hipStream_t stream)
{
    const float* k       = (const float*)d_in[0];
    const float* q       = (const float*)d_in[1];
    const float* W_score = (const float*)d_in[2];
    const float* W_enh   = (const float*)d_in[3];
    const float* b_enh   = (const float*)d_in[4];
    const float* W_mask  = (const float*)d_in[5];
    const float* b_mask  = (const float*)d_in[6];
    float* out = (float*)d_out;

    const size_t MH = (size_t)B_ * T_ * H_;          // 4.096M elems
    unsigned short* q2h = (unsigned short*)d_ws;
    unsigned short* q2l = q2h + MH;
    unsigned short* ch  = q2l + MH;
    unsigned short* cl  = ch + MH;
    unsigned short* kh  = cl + MH;
    unsigned short* kl  = kh + MH;
    unsigned short* ktn = kl + MH;                   // 8*16*126*256
    unsigned short* wsnh = ktn + (size_t)B_ * 16 * 126 * 256;
    unsigned short* wsnl = wsnh + 65536;
    unsigned short* wenh = wsnl + 65536;
    unsigned short* wenl = wenh + 131072;
    unsigned short* wmnh = wenl + 131072;            // 320x256 frag-ordered
    unsigned short* wmnl = wmnh + 81920;

    dim3 blk(256);

    prep<<<dim3(4288), blk, 0, stream>>>(
        k, q, W_score, W_enh, W_mask,
        q2h, q2l, kh, kl, ktn, wsnh, wsnl, wenh, wenl, wmnh, wmnl);

    band_attn_mfma<<<dim3(1000), blk, 0, stream>>>(
        q2h, q2l, wsnh, wsnl, kh, kl, ktn, ch, cl);

    gemm_enh_out<<<dim3(500), dim3(512), 0, stream>>>(
        ch, cl, q2h, q2l, wenh, wenl, b_enh, wmnh, wmnl, b_mask, out);
}

// Round 13
// 119.691 us; speedup vs baseline: 1.0695x; 1.0695x over previous
//
#include <hip/hip_runtime.h>
#include <math.h>

#define B_    8
#define T_    2000
#define H_    256
#define FOUT_ 257
#define ALEN_ 128

typedef __attribute__((ext_vector_type(8))) short bf16x8;
typedef __attribute__((ext_vector_type(4))) float f32x4;
typedef __attribute__((ext_vector_type(16))) float f32x16;
typedef __attribute__((ext_vector_type(8))) unsigned short u16x8;

// ---------------------------------------------------------------------------
// truncation split: x = hi + lo exactly at f32
__device__ __forceinline__ void split1(float x, unsigned short& h, unsigned short& l) {
    unsigned u = __builtin_bit_cast(unsigned, x);
    h = (unsigned short)(u >> 16);
    float hf = __builtin_bit_cast(float, u & 0xFFFF0000u);
    l = (unsigned short)(__builtin_bit_cast(unsigned, x - hf) >> 16);
}
__device__ __forceinline__ void split8(float4 f0, float4 f1, bf16x8& h, bf16x8& l) {
    float f[8] = {f0.x, f0.y, f0.z, f0.w, f1.x, f1.y, f1.z, f1.w};
#pragma unroll
    for (int i = 0; i < 8; ++i) {
        unsigned short hh, ll;
        split1(f[i], hh, ll);
        h[i] = (short)hh; l[i] = (short)ll;
    }
}
__device__ __forceinline__ void gld16(const void* g, void* l) {
    __builtin_amdgcn_global_load_lds(
        (const __attribute__((address_space(1))) unsigned*)g,
        (__attribute__((address_space(3))) unsigned*)l, 16, 0, 0);
}

// ---------------------------------------------------------------------------
// prep (R11-proven):
//  [0,2000):    qsplit  q -> q2h/q2l
//  [2000,3008): k -> kh/kl (row-major split) + ktn (PV-frag-ordered bf16-hi)
//  [3008,3264): W_score -> wsn frag-ordered (attn phase0 B)
//  [3264,3776): W_enh split (row-major, gemm staging)
//  [3776,4288): W_mask -> wmn frag-ordered (stage-2 B); rows 257..319 zero.
__global__ __launch_bounds__(256) void prep(
    const float* __restrict__ k, const float* __restrict__ q,
    const float* __restrict__ Ws, const float* __restrict__ We,
    const float* __restrict__ Wm,
    unsigned short* __restrict__ q2h, unsigned short* __restrict__ q2l,
    unsigned short* __restrict__ kh, unsigned short* __restrict__ kl,
    unsigned short* __restrict__ ktn,
    unsigned short* __restrict__ wsnh, unsigned short* __restrict__ wsnl,
    unsigned short* __restrict__ weh, unsigned short* __restrict__ wel,
    unsigned short* __restrict__ wmnh, unsigned short* __restrict__ wmnl)
{
    __shared__ float tile[16][260];
    const int bx = blockIdx.x, tid = threadIdx.x;

    if (bx < 2000) {                     // ---- qsplit
        const size_t i = ((size_t)bx * 256 + tid) * 8;
        const float4 f0 = *(const float4*)(q + i);
        const float4 f1 = *(const float4*)(q + i + 4);
        bf16x8 h, l;
        split8(f0, f1, h, l);
        *(bf16x8*)(q2h + i) = h;
        *(bf16x8*)(q2l + i) = l;
    } else if (bx < 3008) {              // ---- k prep
        const int bid = bx - 2000;
        const int b = bid / 126;
        const int g = bid % 126;
        const int s0 = g * 16;
        const int r = tid >> 4, cs = (tid & 15) * 16;
        const int s = s0 + r;
        if (s < T_) {
            const size_t ko = ((size_t)b * T_ + s) * H_ + cs;
            const float* src = k + ko;
#pragma unroll
            for (int i = 0; i < 2; ++i) {
                const float4 v0 = *(const float4*)(src + i * 8);
                const float4 v1 = *(const float4*)(src + i * 8 + 4);
                bf16x8 h, l;
                split8(v0, v1, h, l);
                *(bf16x8*)(kh + ko + i * 8) = h;
                *(bf16x8*)(kl + ko + i * 8) = l;
                const float ff[8] = {v0.x, v0.y, v0.z, v0.w, v1.x, v1.y, v1.z, v1.w};
#pragma unroll
                for (int j = 0; j < 8; ++j) tile[r][cs + i * 8 + j] = ff[j];
            }
        } else {
#pragma unroll
            for (int i = 0; i < 16; ++i) tile[r][cs + i] = 0.f;
        }
        __syncthreads();
        const int h = tid;
        const int ht = h >> 4, lq = h & 15;
        u16x8 o0, o1;
#pragma unroll
        for (int ss = 0; ss < 8; ++ss)
            o0[ss] = (unsigned short)(__builtin_bit_cast(unsigned, tile[ss][h]) >> 16);
#pragma unroll
        for (int ss = 0; ss < 8; ++ss)
            o1[ss] = (unsigned short)(__builtin_bit_cast(unsigned, tile[ss + 8][h]) >> 16);
        unsigned short* dst = ktn + (((size_t)(b * 16 + ht) * 126) + g) * 256 + lq * 8;
        *(u16x8*)(dst) = o0;
        *(u16x8*)(dst + 128) = o1;
    } else if (bx < 3264) {              // ---- W_score -> wsn
        const int g = bx - 3008;
        const int hcol = tid;
        unsigned short h, l; split1(Ws[g * 256 + hcol], h, l);
        const int ht = g >> 4, lq = g & 15;
        const int kg = hcol >> 5, lk = (hcol >> 3) & 3, e = hcol & 7;
        const int off = ((ht * 8 + kg) * 64 + lk * 16 + lq) * 8 + e;
        wsnh[off] = h; wsnl[off] = l;
    } else if (bx < 3776) {              // ---- W_enh (row-major split)
        const int idx = (bx - 3264) * 256 + tid;
        unsigned short h, l; split1(We[idx], h, l);
        weh[idx] = h; wel[idx] = l;
    } else {                             // ---- W_mask -> wmn (rows < 320)
        const int r2 = bx - 3776;        // row (out col) 0..511
        if (r2 < 320) {
            const float x = (r2 < FOUT_) ? Wm[r2 * 256 + tid] : 0.f;
            unsigned short h, l; split1(x, h, l);
            const int nt = r2 >> 5, lm2 = r2 & 31;
            const int f = tid >> 4, hh2 = (tid >> 3) & 1, e = tid & 7;
            const int off = (((nt * 16 + f) * 2 + hh2) * 32 + lm2) * 8 + e;
            wmnh[off] = h; wmnl[off] = l;
        }
    }
}

// ---------------------------------------------------------------------------
// Fused banded attention (R11-proven, unchanged).
__global__ __launch_bounds__(256) void band_attn_mfma(
    const unsigned short* __restrict__ q2h, const unsigned short* __restrict__ q2l,
    const unsigned short* __restrict__ wsnh, const unsigned short* __restrict__ wsnl,
    const unsigned short* __restrict__ kh, const unsigned short* __restrict__ kl,
    const unsigned short* __restrict__ ktn,
    unsigned short* __restrict__ Ch, unsigned short* __restrict__ Cl)
{
    __shared__ float S[16][164];
    __shared__ unsigned short PH[16][168];
    __shared__ unsigned short PL[16][168];
    __shared__ unsigned short QSH[16 * 256];
    __shared__ unsigned short QSL[16 * 256];

    const int bid = blockIdx.x;
    const int b = bid & 7;
    const int t0 = (bid >> 3) * 16;
    const int tid = threadIdx.x;
    const int w = tid >> 6, l = tid & 63;
    const int lq = l & 15;
    const int lk = l >> 4;
    const int s_lo = max(0, t0 - ALEN_);
    const size_t qrow = (size_t)b * T_ + t0;
    const size_t kb = (size_t)b * T_ * H_;

    // ---- phase 0: qs tile = q2[16 rows] @ Ws^T (3-term), D -> LDS ----
    {
        bf16x8 aH[8], aL[8];
#pragma unroll
        for (int kg = 0; kg < 8; ++kg) {
            const size_t o = (qrow + lq) * H_ + kg * 32 + lk * 8;
            aH[kg] = *(const bf16x8*)(q2h + o);
            aL[kg] = *(const bf16x8*)(q2l + o);
        }
        for (int ht = w; ht < 16; ht += 4) {
            f32x4 acc = {};
#pragma unroll
            for (int kg = 0; kg < 8; ++kg) {
                const int fo = ((ht * 8 + kg) * 64 + lk * 16 + lq) * 8;
                const bf16x8 bh = *(const bf16x8*)(wsnh + fo);
                const bf16x8 bl = *(const bf16x8*)(wsnl + fo);
                acc = __builtin_amdgcn_mfma_f32_16x16x32_bf16(aH[kg], bh, acc, 0, 0, 0);
                acc = __builtin_amdgcn_mfma_f32_16x16x32_bf16(aH[kg], bl, acc, 0, 0, 0);
                acc = __builtin_amdgcn_mfma_f32_16x16x32_bf16(aL[kg], bh, acc, 0, 0, 0);
            }
#pragma unroll
            for (int r = 0; r < 4; ++r) {
                unsigned short h2, l2;
                split1(acc[r], h2, l2);
                const int t = lk * 4 + r;
                unsigned off = (unsigned)(t * 512 + (ht * 16 + lq) * 2);
                off ^= (unsigned)((t & 7) << 4);
                *(unsigned short*)((char*)QSH + off) = h2;
                *(unsigned short*)((char*)QSL + off) = l2;
            }
        }
    }
    __syncthreads();

    // ---- QK^T ----
    bf16x8 aH[8], aL[8];
#pragma unroll
    for (int hc = 0; hc < 8; ++hc) {
        unsigned off = (unsigned)(lq * 512 + hc * 64 + lk * 16);
        off ^= (unsigned)((lq & 7) << 4);
        aH[hc] = *(const bf16x8*)((const char*)QSH + off);
        aL[hc] = *(const bf16x8*)((const char*)QSL + off);
    }
    for (int st = w; st < 9; st += 4) {
        f32x4 acc = {};
        const int s = s_lo + st * 16 + lq;
        const size_t ro = kb + (size_t)s * H_ + lk * 8;
#pragma unroll
        for (int hc = 0; hc < 8; ++hc) {
            const bf16x8 bh = *(const bf16x8*)(kh + ro + hc * 32);
            const bf16x8 bl = *(const bf16x8*)(kl + ro + hc * 32);
            acc = __builtin_amdgcn_mfma_f32_16x16x32_bf16(aH[hc], bh, acc, 0, 0, 0);
            acc = __builtin_amdgcn_mfma_f32_16x16x32_bf16(aH[hc], bl, acc, 0, 0, 0);
            acc = __builtin_amdgcn_mfma_f32_16x16x32_bf16(aL[hc], bh, acc, 0, 0, 0);
        }
#pragma unroll
        for (int r = 0; r < 4; ++r)
            S[lk * 4 + r][st * 16 + lq] = acc[r];
    }
    __syncthreads();

    // ---- softmax (band-masked, P pre-scaled by 1/denom) ----
    {
        const int q = tid >> 4, li = tid & 15;
        const int t = t0 + q;
        const int jlo = max(0, t - ALEN_) - s_lo;
        const int jhi = t - s_lo;
        float m = -INFINITY;
#pragma unroll
        for (int j = 0; j < 10; ++j) {
            const int s = li + j * 16;
            if (s >= jlo && s <= jhi) m = fmaxf(m, S[q][s]);
        }
#pragma unroll
        for (int off = 8; off; off >>= 1) m = fmaxf(m, __shfl_xor(m, off));
        float sum = 0.f;
#pragma unroll
        for (int j = 0; j < 10; ++j) {
            const int s = li + j * 16;
            const float e = (s >= jlo && s <= jhi) ? expf(S[q][s] - m) : 0.f;
            S[q][s] = e;
            sum += e;
        }
#pragma unroll
        for (int off = 8; off; off >>= 1) sum += __shfl_xor(sum, off);
        const float inv = 1.f / (sum + 1e-30f);
#pragma unroll
        for (int j = 0; j < 10; ++j) {
            const int s = li + j * 16;
            unsigned short hh2, ll2;
            split1(S[q][s] * inv, hh2, ll2);
            PH[q][s] = hh2;
            PL[q][s] = ll2;
        }
    }
    __syncthreads();

    // ---- PV (frag-ordered ktn) ----
    const int gbase = s_lo >> 4;
    for (int ht = w; ht < 16; ht += 4) {
        f32x4 acc = {};
        const unsigned short* ktb = ktn + ((size_t)(b * 16 + ht) * 126) * 256;
#pragma unroll
        for (int sc = 0; sc < 5; ++sc) {
            const bf16x8 ph = *(const bf16x8*)((const char*)&PH[lq][0] + sc * 64 + lk * 16);
            const bf16x8 pl = *(const bf16x8*)((const char*)&PL[lq][0] + sc * 64 + lk * 16);
            const bf16x8 bt = *(const bf16x8*)(
                ktb + (size_t)(gbase + 2 * sc + (lk >> 1)) * 256 + (lk & 1) * 128 + lq * 8);
            acc = __builtin_amdgcn_mfma_f32_16x16x32_bf16(ph, bt, acc, 0, 0, 0);
            acc = __builtin_amdgcn_mfma_f32_16x16x32_bf16(pl, bt, acc, 0, 0, 0);
        }
#pragma unroll
        for (int r = 0; r < 4; ++r) {
            unsigned short hh2, ll2;
            split1(acc[r], hh2, ll2);
            const size_t o = (qrow + lk * 4 + r) * H_ + ht * 16 + lq;
            Ch[o] = hh2;
            Cl[o] = ll2;
        }
    }
}

// ---------------------------------------------------------------------------
// Fused enh+out GEMM v3: R11 structure (W staged in LDS, 80KB, BK=32, BM=64,
// BN=256) but 512 threads / 8 waves: wave tile 32x64 (wr=w>>2 row-block,
// wc=w&3 col-block). Halves per-wave MFMA chain, doubles waves/SIMD.
// Arithmetic and K-order identical to R11.
__global__ __launch_bounds__(512, 2) void gemm_enh_out(
    const unsigned short* __restrict__ Ah1, const unsigned short* __restrict__ Al1,
    const unsigned short* __restrict__ Ah2, const unsigned short* __restrict__ Al2,
    const unsigned short* __restrict__ Wh, const unsigned short* __restrict__ Wl,
    const float* __restrict__ b_enh,
    const unsigned short* __restrict__ wmnh, const unsigned short* __restrict__ wmnl,
    const float* __restrict__ b_mask, float* __restrict__ out)
{
    __shared__ char LDSB[80 * 1024];
    // main loop: AS buf0 @0 (8KB), buf1 @8K; WS buf0 @16K (32KB), buf1 @48K.
    // after: EH @0 (32KB), EL @32K (32KB).

    const int tid = threadIdx.x;
    const int m0 = blockIdx.x * 64;
    const int w = tid >> 6, l = tid & 63;
    const int lm = l & 31, hh = l >> 5;
    const int wr = w >> 2, wc = w & 3;
    constexpr int KB = 512, NT = 16;

    f32x16 acc0 = {}, acc1 = {};

    auto STAGEA = [&](int kt, int buf) {
        const int k0g = kt * 32;
        const unsigned short* Hs = Ah1;
        const unsigned short* Ls = Al1;
        int k0 = k0g;
        if (k0g >= 256) { Hs = Ah2; Ls = Al2; k0 = k0g - 256; }
        const unsigned D = (unsigned)tid * 16u;          // 0..8191
        const unsigned row = D >> 7;                     // 0..63
        const unsigned u = (D & 127u) ^ ((row & 7u) << 4);
        const unsigned kelem = (u & 63u) >> 1;
        const unsigned short* src =
            ((u >> 6) ? Ls : Hs) + (size_t)(m0 + row) * 256 + k0 + kelem;
        gld16(src, LDSB + buf * 8192 + (size_t)w * 1024);
    };
    auto STAGEW = [&](int kt, int buf) {
        const int k0g = kt * 32;
#pragma unroll
        for (int p = 0; p < 4; ++p) {
            const unsigned D = p * 8192u + (unsigned)tid * 16u;
            const unsigned row = D >> 7;                 // 0..255
            const unsigned u = (D & 127u) ^ ((row & 7u) << 4);
            const unsigned kelem = (u & 63u) >> 1;
            const unsigned short* src =
                ((u >> 6) ? Wl : Wh) + (size_t)row * KB + k0g + kelem;
            gld16(src, LDSB + 16 * 1024 + buf * 32768 + (size_t)(p * 8 + w) * 1024);
        }
    };

    STAGEA(0, 0);
    STAGEW(0, 0);
    __syncthreads();

    int buf = 0;
    for (int kt = 0; kt < NT; ++kt) {
        const bool last = (kt == NT - 1);
        if (!last) { STAGEA(kt + 1, buf ^ 1); STAGEW(kt + 1, buf ^ 1); }

        const char* As = LDSB + buf * 8192;
        const char* Wsb = LDSB + 16 * 1024 + buf * 32768;
        const unsigned r_a = (unsigned)(wr * 32 + lm);   // 0..63
        const unsigned swa = (r_a & 7u) << 4;
        const unsigned r_b = (unsigned)(wc * 64 + lm);   // col blocks +0, +32
        const unsigned swb = (r_b & 7u) << 4;
#pragma unroll
        for (int kc = 0; kc < 2; ++kc) {
            const unsigned u = (unsigned)(kc * 32 + hh * 16);
            const bf16x8 ah = *(const bf16x8*)(As + r_a * 128 + (u ^ swa));
            const bf16x8 al = *(const bf16x8*)(As + r_a * 128 + ((u + 64) ^ swa));
            const bf16x8 bh0 = *(const bf16x8*)(Wsb + r_b * 128 + (u ^ swb));
            const bf16x8 bl0 = *(const bf16x8*)(Wsb + r_b * 128 + ((u + 64) ^ swb));
            const bf16x8 bh1 = *(const bf16x8*)(Wsb + (r_b + 32) * 128 + (u ^ swb));
            const bf16x8 bl1 = *(const bf16x8*)(Wsb + (r_b + 32) * 128 + ((u + 64) ^ swb));
            acc0 = __builtin_amdgcn_mfma_f32_32x32x16_bf16(ah, bh0, acc0, 0, 0, 0);
            acc0 = __builtin_amdgcn_mfma_f32_32x32x16_bf16(ah, bl0, acc0, 0, 0, 0);
            acc0 = __builtin_amdgcn_mfma_f32_32x32x16_bf16(al, bh0, acc0, 0, 0, 0);
            acc1 = __builtin_amdgcn_mfma_f32_32x32x16_bf16(ah, bh1, acc1, 0, 0, 0);
            acc1 = __builtin_amdgcn_mfma_f32_32x32x16_bf16(ah, bl1, acc1, 0, 0, 0);
            acc1 = __builtin_amdgcn_mfma_f32_32x32x16_bf16(al, bh1, acc1, 0, 0, 0);
        }
        __syncthreads();
        buf ^= 1;
    }

    // enh tile -> LDS (split, swizzled). D: col=lane&31, row=(e&3)+8*(e>>2)+4*hh
    {
        char* EH = LDSB;
        char* EL = LDSB + 32 * 1024;
#pragma unroll
        for (int ct = 0; ct < 2; ++ct) {
            const f32x16 r = ct ? acc1 : acc0;
            const int col = wc * 64 + ct * 32 + lm;      // 0..255
            const float bv = b_enh[col];
#pragma unroll
            for (int e = 0; e < 16; ++e) {
                const int row = wr * 32 + (e & 3) + 8 * (e >> 2) + 4 * hh;
                unsigned short h2, l2;
                split1(tanhf(r[e] + bv), h2, l2);
                unsigned off = (unsigned)(row * 512 + col * 2);
                off ^= (unsigned)((row & 7) << 4);
                *(unsigned short*)(EH + off) = h2;
                *(unsigned short*)(EL + off) = l2;
            }
        }
    }
    __syncthreads();

    // out = sigmoid(enh @ Wm^T + bm); wave w: nt = w (and w+8 for w<2)
    for (int nt = w; nt < 10; nt += 8) {
        const char* EH = LDSB;
        const char* EL = LDSB + 32 * 1024;
        f32x16 o0 = {}, o1 = {};
#pragma unroll
        for (int f = 0; f < 16; ++f) {
            const unsigned kb2 = (unsigned)(f * 32 + hh * 16);
            const unsigned row0 = (unsigned)lm;
            const unsigned sw = (row0 & 7u) << 4;        // (row0+32)&7 == row0&7
            const unsigned offA0 = row0 * 512 + kb2;
            const unsigned offA1 = (row0 + 32) * 512 + kb2;
            const bf16x8 ah0 = *(const bf16x8*)(EH + (offA0 ^ sw));
            const bf16x8 al0 = *(const bf16x8*)(EL + (offA0 ^ sw));
            const bf16x8 ah1 = *(const bf16x8*)(EH + (offA1 ^ sw));
            const bf16x8 al1 = *(const bf16x8*)(EL + (offA1 ^ sw));
            const size_t bo = (((size_t)(nt * 16 + f) * 2 + hh) * 32 + lm) * 8;
            const bf16x8 bh = *(const bf16x8*)(wmnh + bo);
            const bf16x8 bl = *(const bf16x8*)(wmnl + bo);
            o0 = __builtin_amdgcn_mfma_f32_32x32x16_bf16(ah0, bh, o0, 0, 0, 0);
            o0 = __builtin_amdgcn_mfma_f32_32x32x16_bf16(ah0, bl, o0, 0, 0, 0);
            o0 = __builtin_amdgcn_mfma_f32_32x32x16_bf16(al0, bh, o0, 0, 0, 0);
            o1 = __builtin_amdgcn_mfma_f32_32x32x16_bf16(ah1, bh, o1, 0, 0, 0);
            o1 = __builtin_amdgcn_mfma_f32_32x32x16_bf16(ah1, bl, o1, 0, 0, 0);
            o1 = __builtin_amdgcn_mfma_f32_32x32x16_bf16(al1, bh, o1, 0, 0, 0);
        }
        const int gcol = nt * 32 + lm;
        if (gcol < FOUT_) {
            const float bv = b_mask[gcol];
#pragma unroll
            for (int e = 0; e < 16; ++e) {
                const int rowl = (e & 3) + 8 * (e >> 2) + 4 * hh;
                out[(size_t)(m0 + rowl) * FOUT_ + gcol] = 1.f / (1.f + expf(-(o0[e] + bv)));
                out[(size_t)(m0 + 32 + rowl) * FOUT_ + gcol] = 1.f / (1.f + expf(-(o1[e] + bv)));
            }
        }
    }
}

// ---------------------------------------------------------------------------
extern "C" void kernel_launch(void* const* d_in, const int* in_sizes, int n_in,
                              void* d_out, int out_size, void* d_ws, size_t ws_size,
                              hipStream_t stream)
{
    const float* k       = (const float*)d_in[0];
    const float* q       = (const float*)d_in[1];
    const float* W_score = (const float*)d_in[2];
    const float* W_enh   = (const float*)d_in[3];
    const float* b_enh   = (const float*)d_in[4];
    const float* W_mask  = (const float*)d_in[5];
    const float* b_mask  = (const float*)d_in[6];
    float* out = (float*)d_out;

    const size_t MH = (size_t)B_ * T_ * H_;          // 4.096M elems
    unsigned short* q2h = (unsigned short*)d_ws;
    unsigned short* q2l = q2h + MH;
    unsigned short* ch  = q2l + MH;
    unsigned short* cl  = ch + MH;
    unsigned short* kh  = cl + MH;
    unsigned short* kl  = kh + MH;
    unsigned short* ktn = kl + MH;                   // 8*16*126*256
    unsigned short* wsnh = ktn + (size_t)B_ * 16 * 126 * 256;
    unsigned short* wsnl = wsnh + 65536;
    unsigned short* weh  = wsnl + 65536;
    unsigned short* wel  = weh + 131072;
    unsigned short* wmnh = wel + 131072;             // 320x256 frag-ordered
    unsigned short* wmnl = wmnh + 81920;

    dim3 blk(256);

    prep<<<dim3(4288), blk, 0, stream>>>(
        k, q, W_score, W_enh, W_mask,
        q2h, q2l, kh, kl, ktn, wsnh, wsnl, weh, wel, wmnh, wmnl);

    band_attn_mfma<<<dim3(1000), blk, 0, stream>>>(
        q2h, q2l, wsnh, wsnl, kh, kl, ktn, ch, cl);

    gemm_enh_out<<<dim3(250), dim3(512), 0, stream>>>(
        ch, cl, q2h, q2l, weh, wel, b_enh, wmnh, wmnl, b_mask, out);
}